// Round 8
// baseline (157.162 us; speedup 1.0000x reference)
//
#include <hip/hip_runtime.h>

// SE_loss_w_threshold: h,v (8,16384,128) fp32, N scalar.
// out[0]=mean(Rp), out[1..8]=R_per_user_p, out[9]=sum(R_per_user_p)
//
// v8: zero-register software pipeline via global_load_lds + double buffer.
//   v7 post-mortem: L3-resident replay dispatches ran at IDENTICAL speed
//   (~50us) with hbm_bytes ~131KB -> kernel is NOT memory-system-bound;
//   the serializer is the per-phase on-chip chain
//   {gload -> vmcnt(0) -> ds_write -> lgkm -> 32 ds_read}, which idles the
//   LDS pipe (the largest consumer: ~47% busy) during every load wait.
//   Occupancy 35->50% changed nothing (v1 vs v7) -> more waves don't help
//   a lockstep chain. Register prefetch is unaffordable (v4/v5/v6 spills,
//   64-VGPR cap). Fix: global_load_lds DMA (no VGPRs!) into 2 per-wave
//   4KB tiles; issue next phase's 4 DMAs, then counted s_waitcnt vmcnt(4)
//   so current tile is ready while next tile's loads fly under the k-loop.
//   Also deletes all ds_writes (72 -> 68 LDS ops/batch).
//   Bank conflicts: DMA dest must be LINEAR (no padding), so each row's
//   16B slots are ROTATED by user index at the global SOURCE (pre-swizzled
//   source pattern); reads apply the same rotation: read banks
//   4*((c+u)&7) distinct across the 8 user groups => conflict-free.
//   nsq: read back from LDS in the EXACT v7 register order (2 extra b128
//   reads/phase, knowingly 8-way conflicted -- cheap) => bitwise-identical
//   A/R/nsq math to v7 (absmax 0.0 expected).

constexpr int U_    = 8;
constexpr int B_    = 16384;
constexpr int NT_   = 128;
constexpr int NBLK_ = 2048;
constexpr int WPB_  = 4;              // waves per block (256 threads)
constexpr int TW_   = NBLK_ * WPB_;   // 8192 waves
constexpr int IT_   = B_ / TW_;       // 2 batches per wave
constexpr size_t UST_ = (size_t)B_ * NT_;  // user stride (floats)
constexpr float T_THRESH = 0.3f;
constexpr float LOG2_10  = 3.3219280948873623f;

typedef __attribute__((address_space(3))) void lds_void;
typedef const __attribute__((address_space(1))) void g_void;

__device__ __forceinline__ void gload16(const float* g, float* l) {
    // 16B per lane: global (per-lane addr) -> LDS (wave-uniform base + lane*16)
    __builtin_amdgcn_global_load_lds((g_void*)g, (lds_void*)l, 16, 0, 0);
}

__device__ __forceinline__ float waveReduceSum(float v) {
    #pragma unroll
    for (int m = 1; m < 64; m <<= 1) v += __shfl_xor(v, m, 64);
    return v;
}

__device__ __forceinline__ float hw_log2(float x) { return __builtin_amdgcn_logf(x); }
__device__ __forceinline__ float hw_exp2(float x) { return __builtin_amdgcn_exp2f(x); }

__global__ __launch_bounds__(256, 4) void se_main(const float* __restrict__ h,
                                                  const float* __restrict__ vv,
                                                  const float* __restrict__ Np,
                                                  float* __restrict__ partial) {
    // Per-wave: 2 tiles x {h,v} x [16 rows][32 floats] (half-k, linear, no pad).
    // Row r = 2u+p (p: 0=re,1=im); slot s (16B) of row r holds global chunk
    // (s - (r>>1)) & 7  == source-rotated so reads at slot (c + u)&7 are
    // bank-conflict-free.
    __shared__ __align__(16) float lds[WPB_][2][2][512];
    __shared__ float red_f[WPB_];
    __shared__ float red_R[WPB_][U_];

    const int tid  = threadIdx.x;
    const int wave = tid >> 6;
    const int lane = tid & 63;
    const int ui   = lane >> 3;   // user i (row of A)
    const int uj   = lane & 7;    // user j (col of A)
    const float Nval = Np[0];

    const int gwave = blockIdx.x * WPB_ + wave;

    // ---- per-lane staging source offsets (2 DMA instrs per array) ----
    // instr q covers tile rows q*8 .. q*8+7; lane l -> row q*8 + (l>>3), slot l&7.
    const int u0 = lane >> 4;            // q=0: user = l>>4      (rows 0..7)
    const int p_ = (lane >> 3) & 1;      // re/im plane
    const int s_ = lane & 7;
    const int g0 = (s_ - u0) & 7;        // source chunk for q=0 (rotation u0)
    const int g1 = (s_ - (u0 + 4)) & 7;  // q=1: user = u0+4
    const size_t off0 = (size_t)u0 * UST_ + (size_t)(p_ * 64 + g0 * 4);
    const size_t off1 = (size_t)(u0 + 4) * UST_ + (size_t)(p_ * 64 + g1 * 4);
    const float* h0 = h  + off0;  const float* h1 = h  + off1;
    const float* v0 = vv + off0;  const float* v1 = vv + off1;

    float (*T0)[512] = lds[wave][0];   // T0[0]=h tile, T0[1]=v tile
    float (*T1)[512] = lds[wave][1];

    float lane_sumR = 0.0f;
    float lane_sumf = 0.0f;

    // ---- prologue: stage phase 0 (batch gwave, k-half 0) into T0 ----
    {
        const size_t po = (size_t)gwave * NT_;
        gload16(h0 + po, &T0[0][0]);   gload16(h1 + po, &T0[0][256]);
        gload16(v0 + po, &T0[1][0]);   gload16(v1 + po, &T0[1][256]);
    }

    #pragma unroll
    for (int it = 0; it < IT_; ++it) {
        float nsq = 0.0f, are = 0.0f, aim = 0.0f;
        #pragma unroll
        for (int x = 0; x < 2; ++x) {
            const int ph = it * 2 + x;                 // 0..3, compile-time
            float (*TC)[512] = (ph & 1) ? T1 : T0;     // current tile
            float (*TN)[512] = (ph & 1) ? T0 : T1;     // next tile

            if (ph < 2 * IT_ - 1) {
                // issue next phase's 4 DMAs, then wait ONLY for current tile
                const int bn = gwave + ((ph + 1) >> 1) * TW_;
                const int xn = (ph + 1) & 1;
                const size_t po = (size_t)bn * NT_ + (size_t)(xn * 32);
                gload16(h0 + po, &TN[0][0]);   gload16(h1 + po, &TN[0][256]);
                gload16(v0 + po, &TN[1][0]);   gload16(v1 + po, &TN[1][256]);
                asm volatile("s_waitcnt vmcnt(4)" ::: "memory");
            } else {
                asm volatile("s_waitcnt vmcnt(0)" ::: "memory");
            }
            __builtin_amdgcn_sched_barrier(0);

            // ---- nsq in EXACT v7 register order: global chunk uj of v rows
            //      2ui (re) / 2ui+1 (im); rotation of row 2u is u ----
            const float* vrow = &TC[1][ui * 64];
            const float4 rv0 = *reinterpret_cast<const float4*>(vrow + ((uj + ui) & 7) * 4);
            const float4 rv1 = *reinterpret_cast<const float4*>(vrow + 32 + ((uj + ui) & 7) * 4);
            nsq += rv0.x * rv0.x + rv0.y * rv0.y + rv0.z * rv0.z + rv0.w * rv0.w
                 + rv1.x * rv1.x + rv1.y * rv1.y + rv1.z * rv1.z + rv1.w * rv1.w;

            // ---- A[i][j] partial over this k-half (global k ascending) ----
            const float* ha = &TC[0][ui * 64];
            const float* va = &TC[1][uj * 64];
            #pragma unroll
            for (int c = 0; c < 8; ++c) {
                const int hs = ((c + ui) & 7) * 4;   // rotated slot for h row ui
                const int vs = ((c + uj) & 7) * 4;   // rotated slot for v row uj
                const float4 hr = *reinterpret_cast<const float4*>(ha + hs);
                const float4 hi = *reinterpret_cast<const float4*>(ha + 32 + hs);
                const float4 vr = *reinterpret_cast<const float4*>(va + vs);
                const float4 vi = *reinterpret_cast<const float4*>(va + 32 + vs);
                are += hr.x * vr.x + hi.x * vi.x;
                aim += hi.x * vr.x - hr.x * vi.x;
                are += hr.y * vr.y + hi.y * vi.y;
                aim += hi.y * vr.y - hr.y * vi.y;
                are += hr.z * vr.z + hi.z * vi.z;
                aim += hi.z * vr.z - hr.z * vi.z;
                are += hr.w * vr.w + hi.w * vi.w;
                aim += hi.w * vr.w - hr.w * vi.w;
            }
        }

        // ---- finish batch (identical to v1/v7) ----
        const float normsq = waveReduceSum(nsq);
        const float Iall = are * are + aim * aim;

        const float diag = __shfl(Iall, ui * 9, 64);
        float rowsum = Iall;
        rowsum += __shfl_xor(rowsum, 1, 64);
        rowsum += __shfl_xor(rowsum, 2, 64);
        rowsum += __shfl_xor(rowsum, 4, 64);

        const float Ip   = rowsum - diag;
        const float S    = (8.0f / normsq) * diag;
        const float SINR = S / (Ip + Nval);
        const float R    = hw_log2(1.0f + SINR);

        lane_sumR += R;
        lane_sumf += hw_exp2((T_THRESH - R) * LOG2_10) - R;
    }

    // ---- block-level reduction (identical to v7) ----
    const float wf = waveReduceSum(lane_sumf) * 0.125f;  // each user counted 8x
    if (lane == 0) red_f[wave] = wf;
    if (uj == 0)   red_R[wave][ui] = lane_sumR;
    __syncthreads();

    if (tid < U_) {
        float s = 0.0f;
        #pragma unroll
        for (int w = 0; w < WPB_; ++w) s += red_R[w][tid];
        partial[blockIdx.x * 9 + 1 + tid] = s;
    } else if (tid == U_) {
        float s = 0.0f;
        #pragma unroll
        for (int w = 0; w < WPB_; ++w) s += red_f[w];
        partial[blockIdx.x * 9] = s;
    }
}

__global__ __launch_bounds__(1024) void se_final(const float* __restrict__ partial,
                                                 float* __restrict__ out) {
    // 2048 partial rows: each of 1024 threads folds 2 rows, then
    // deterministic wave trees + fixed cross-wave order (no atomics).
    __shared__ float acc[16][9];
    const int tid = threadIdx.x, w = tid >> 6, l = tid & 63;

    float v[9];
    #pragma unroll
    for (int s = 0; s < 9; ++s)
        v[s] = partial[tid * 9 + s] + partial[(tid + 1024) * 9 + s];

    #pragma unroll
    for (int s = 0; s < 9; ++s) {
        float t = v[s];
        #pragma unroll
        for (int m = 1; m < 64; m <<= 1) t += __shfl_xor(t, m, 64);
        if (l == 0) acc[w][s] = t;
    }
    __syncthreads();

    if (tid == 0) {
        float sums[9];
        #pragma unroll
        for (int s = 0; s < 9; ++s) {
            float t = acc[0][s];
            #pragma unroll
            for (int ww = 1; ww < 16; ++ww) t += acc[ww][s];
            sums[s] = t;
        }
        const float inv = 1.0f / (float)B_;
        out[0] = sums[0] * inv;          // mean(Rp)
        float tot = 0.0f;
        #pragma unroll
        for (int i = 0; i < U_; ++i) {
            const float r = sums[1 + i] * inv;
            out[1 + i] = r;              // R_per_user_p
            tot += r;
        }
        out[9] = tot;                    // sum(R_per_user_p)
    }
}

extern "C" void kernel_launch(void* const* d_in, const int* in_sizes, int n_in,
                              void* d_out, int out_size, void* d_ws, size_t ws_size,
                              hipStream_t stream) {
    const float* h  = (const float*)d_in[0];
    const float* v  = (const float*)d_in[1];
    const float* Np = (const float*)d_in[2];
    float* out      = (float*)d_out;
    float* partial  = (float*)d_ws;   // NBLK_*9 floats (73728 B), fully overwritten each call

    se_main<<<NBLK_, 256, 0, stream>>>(h, v, Np, partial);
    se_final<<<1, 1024, 0, stream>>>(partial, out);
}